// Round 1
// baseline (1731.560 us; speedup 1.0000x reference)
//
#include <hip/hip_runtime.h>
#include <math.h>

#define N_NODES 100000
#define N_EDGES 6400000
#define F_IN 128
#define F_OUT 16

// -------- 1. degree of target nodes (edge weight 1.0) --------
__global__ void deg_kernel(const int* __restrict__ col, float* __restrict__ deg) {
    int e = blockIdx.x * blockDim.x + threadIdx.x;
    if (e < N_EDGES) atomicAdd(&deg[col[e]], 1.0f);
}

// -------- 2. dinv = rsqrt(deg + 1)   (+1 = self loop; always > 0) --------
__global__ void dinv_kernel(float* __restrict__ deg) {
    int n = blockIdx.x * blockDim.x + threadIdx.x;
    if (n < N_NODES) deg[n] = rsqrtf(deg[n] + 1.0f);
}

// -------- 3. g[n,f] = dinv[n] * sum_k x[n,k] * W[k,f] --------
// 256 threads/block, 16 nodes/block. N_NODES % 16 == 0 (100000 = 6250*16).
__global__ void gemm_kernel(const float* __restrict__ x, const float* __restrict__ W,
                            const float* __restrict__ dinv, float* __restrict__ g) {
    __shared__ float Ws[F_IN * F_OUT];        // 8 KB
    __shared__ float xs[16 * (F_IN + 1)];     // +1 pad breaks 4-way bank conflict
    const int tid = threadIdx.x;
    const int n0 = blockIdx.x * 16;
    for (int i = tid; i < F_IN * F_OUT; i += 256) Ws[i] = W[i];
    const float* xbase = x + (size_t)n0 * F_IN;   // 16 rows are contiguous
    for (int i = tid; i < 16 * F_IN; i += 256) {
        int r = i >> 7, c = i & 127;
        xs[r * (F_IN + 1) + c] = xbase[i];
    }
    __syncthreads();
    const int node = tid >> 4, f = tid & 15;
    const float* xr = &xs[node * (F_IN + 1)];
    float acc = 0.f;
    #pragma unroll 8
    for (int k = 0; k < F_IN; k++) acc += xr[k] * Ws[k * 16 + f];
    g[(size_t)n0 * 16 + tid] = acc * dinv[n0 + node];   // coalesced: global idx = n0*16 + tid
}

// -------- 4. scatter: acc[col] += g[row]  (the expected bottleneck) --------
// One thread per (edge, quarter-row): gather float4 from g, 4 fp32 atomics.
// grid*block == N_EDGES*4 exactly -> no bounds check.
__global__ void scatter_kernel(const int* __restrict__ row, const int* __restrict__ col,
                               const float4* __restrict__ g4, float* __restrict__ acc) {
    const int gid = blockIdx.x * blockDim.x + threadIdx.x;
    const int e = gid >> 2, q = gid & 3;
    const int r = row[e];   // 4 lanes same address -> merged
    const int c = col[e];
    const float4 v = g4[(size_t)r * 4 + q];
    float* dst = acc + (size_t)c * 16 + q * 4;
    atomicAdd(dst + 0, v.x);
    atomicAdd(dst + 1, v.y);
    atomicAdd(dst + 2, v.z);
    atomicAdd(dst + 3, v.w);
}

// -------- 5. out_n = tanh(dinv[n]*(acc[n]+g[n]) + b); mean over n --------
// Grid-stride with stride % 16 == 0 so each thread keeps one fixed f.
__global__ void finalize_kernel(const float* __restrict__ acc, const float* __restrict__ g,
                                const float* __restrict__ dinv, const float* __restrict__ b,
                                double* __restrict__ dsum) {
    __shared__ float s[4][16];
    const int tid = threadIdx.x;
    const int f = tid & 15;
    const float bf = b[f];
    float local = 0.f;
    for (int i = blockIdx.x * blockDim.x + tid; i < N_NODES * F_OUT;
         i += gridDim.x * blockDim.x) {
        const int n = i >> 4;
        local += tanhf(dinv[n] * (acc[i] + g[i]) + bf);
    }
    // lanes {f, f+16, f+32, f+48} share the same feature f
    local += __shfl_down(local, 32);
    local += __shfl_down(local, 16);
    const int lane = tid & 63, wave = tid >> 6;
    if (lane < 16) s[wave][lane] = local;
    __syncthreads();
    if (tid < 16) {
        float v = s[0][tid] + s[1][tid] + s[2][tid] + s[3][tid];
        atomicAdd(&dsum[tid], (double)v);   // 16 addrs x gridDim blocks only
    }
}

__global__ void out_kernel(const double* __restrict__ dsum, float* __restrict__ out) {
    const int f = threadIdx.x;
    if (f < 16) out[f] = (float)(dsum[f] * (1.0 / (double)N_NODES));
}

extern "C" void kernel_launch(void* const* d_in, const int* in_sizes, int n_in,
                              void* d_out, int out_size, void* d_ws, size_t ws_size,
                              hipStream_t stream) {
    const float* x  = (const float*)d_in[0];
    const int*   ei = (const int*)d_in[1];
    const float* W  = (const float*)d_in[2];
    const float* b  = (const float*)d_in[3];
    float* out = (float*)d_out;

    // workspace layout: [deg/dinv (100000 f32) | acc (1.6M f32) | dsum (16 f64) | g (1.6M f32)]
    float*  deg  = (float*)d_ws;
    float*  acc  = deg + N_NODES;
    double* dsum = (double*)(acc + (size_t)N_NODES * F_OUT);
    float*  g    = (float*)(dsum + 16);

    const int* row = ei;             // edge_index[0] = source
    const int* col = ei + N_EDGES;   // edge_index[1] = target

    // zero deg + acc + dsum in one contiguous memset (g is fully overwritten)
    hipMemsetAsync(deg, 0,
                   (size_t)(N_NODES + (size_t)N_NODES * F_OUT) * sizeof(float) + 16 * sizeof(double),
                   stream);

    deg_kernel<<<(N_EDGES + 255) / 256, 256, 0, stream>>>(col, deg);
    dinv_kernel<<<(N_NODES + 255) / 256, 256, 0, stream>>>(deg);
    gemm_kernel<<<N_NODES / 16, 256, 0, stream>>>(x, W, deg, g);
    scatter_kernel<<<(N_EDGES * 4) / 256, 256, 0, stream>>>(row, col, (const float4*)g, acc);
    finalize_kernel<<<640, 256, 0, stream>>>(acc, g, deg, b, dsum);
    out_kernel<<<1, 16, 0, stream>>>(dsum, out);
}

// Round 2
// 1061.640 us; speedup vs baseline: 1.6310x; 1.6310x over previous
//
#include <hip/hip_runtime.h>
#include <math.h>

#define N_NODES 100000
#define N_EDGES 6400000
#define F_IN 128
#define F_OUT 16
#define NBLK_SCAN 98   // ceil(100000/1024)

// -------- 1. integer degree count of target nodes --------
__global__ void deg_kernel(const int* __restrict__ col, int* __restrict__ cnt) {
    int e = blockIdx.x * blockDim.x + threadIdx.x;
    if (e < N_EDGES) atomicAdd(&cnt[col[e]], 1);
}

// -------- 2. dinv = rsqrt(cnt + 1)   (+1 = self loop; always > 0) --------
__global__ void dinv_kernel(const int* __restrict__ cnt, float* __restrict__ dinv) {
    int n = blockIdx.x * blockDim.x + threadIdx.x;
    if (n < N_NODES) dinv[n] = rsqrtf((float)cnt[n] + 1.0f);
}

// -------- 3. exclusive prefix scan of cnt -> offs (3 kernels) --------
__global__ void scan_a(const int* __restrict__ cnt, int* __restrict__ offs,
                       int* __restrict__ bsum) {
    __shared__ int lds[256];
    const int tid = threadIdx.x;
    const int base = blockIdx.x * 1024 + tid * 4;
    int v[4];
    #pragma unroll
    for (int j = 0; j < 4; j++) { int i = base + j; v[j] = (i < N_NODES) ? cnt[i] : 0; }
    int s = v[0] + v[1] + v[2] + v[3];
    lds[tid] = s; __syncthreads();
    for (int off = 1; off < 256; off <<= 1) {
        int t = (tid >= off) ? lds[tid - off] : 0; __syncthreads();
        lds[tid] += t; __syncthreads();
    }
    if (tid == 255) bsum[blockIdx.x] = lds[255];
    int run = lds[tid] - s;   // exclusive prefix of this thread's 4-chunk
    #pragma unroll
    for (int j = 0; j < 4; j++) { int i = base + j; if (i < N_NODES) offs[i] = run; run += v[j]; }
}

__global__ void scan_b(int* __restrict__ bsum) {   // 1 block, 128 threads
    __shared__ int lds[128];
    const int tid = threadIdx.x;
    int v = (tid < NBLK_SCAN) ? bsum[tid] : 0;
    lds[tid] = v; __syncthreads();
    for (int off = 1; off < 128; off <<= 1) {
        int t = (tid >= off) ? lds[tid - off] : 0; __syncthreads();
        lds[tid] += t; __syncthreads();
    }
    if (tid < NBLK_SCAN) bsum[tid] = lds[tid] - v;  // exclusive
}

__global__ void scan_c(int* __restrict__ offs, const int* __restrict__ bsum,
                       int* __restrict__ cursor) {
    int i = blockIdx.x * blockDim.x + threadIdx.x;
    if (i < N_NODES) {
        int o = offs[i] + bsum[i >> 10];
        offs[i] = o;
        cursor[i] = o;
    }
    if (i == 0) offs[N_NODES] = N_EDGES;
}

// -------- 4. g[n,f] = dinv[n] * sum_k x[n,k] * W[k,f] --------
__global__ void gemm_kernel(const float* __restrict__ x, const float* __restrict__ W,
                            const float* __restrict__ dinv, float* __restrict__ g) {
    __shared__ float Ws[F_IN * F_OUT];        // 8 KB
    __shared__ float xs[16 * (F_IN + 1)];     // +1 pad breaks bank conflict
    const int tid = threadIdx.x;
    const int n0 = blockIdx.x * 16;
    for (int i = tid; i < F_IN * F_OUT; i += 256) Ws[i] = W[i];
    const float* xbase = x + (size_t)n0 * F_IN;
    for (int i = tid; i < 16 * F_IN; i += 256) {
        int r = i >> 7, c = i & 127;
        xs[r * (F_IN + 1) + c] = xbase[i];
    }
    __syncthreads();
    const int node = tid >> 4, f = tid & 15;
    const float* xr = &xs[node * (F_IN + 1)];
    float acc = 0.f;
    #pragma unroll 8
    for (int k = 0; k < F_IN; k++) acc += xr[k] * Ws[k * 16 + f];
    g[(size_t)n0 * 16 + tid] = acc * dinv[n0 + node];
}

// -------- 5. CSR fill: slot srcs[p] = row[e], grouped by target --------
__global__ void fill_kernel(const int* __restrict__ row, const int* __restrict__ col,
                            int* __restrict__ cursor, int* __restrict__ srcs) {
    int e = blockIdx.x * blockDim.x + threadIdx.x;
    if (e < N_EDGES) {
        int c = col[e];
        int p = atomicAdd(&cursor[c], 1);
        srcs[p] = row[e];
    }
}

// -------- 6. gather-reduce: acc[n,f] = sum over srcs of g[src,f] --------
// 16 lanes per node (lane = feature), 16 nodes per 256-block, NO atomics.
__global__ void gather_kernel(const int* __restrict__ offs, const int* __restrict__ srcs,
                              const float* __restrict__ g, float* __restrict__ acc) {
    const int tid = threadIdx.x;
    const int node = blockIdx.x * 16 + (tid >> 4);
    const int f = tid & 15;
    if (node >= N_NODES) return;
    const int s = offs[node], e = offs[node + 1];
    float a = 0.f;
    int k = s;
    for (; k + 1 < e; k += 2) {               // 2-way unroll: 2 gathers in flight
        int s0 = srcs[k], s1 = srcs[k + 1];
        a += g[(size_t)s0 * 16 + f];
        a += g[(size_t)s1 * 16 + f];
    }
    if (k < e) a += g[(size_t)srcs[k] * 16 + f];
    acc[(size_t)node * 16 + f] = a;           // coalesced 64 B per node
}

// -------- 7. out_n = tanh(dinv[n]*(acc[n]+g[n]) + b); mean over n --------
__global__ void finalize_kernel(const float* __restrict__ acc, const float* __restrict__ g,
                                const float* __restrict__ dinv, const float* __restrict__ b,
                                double* __restrict__ dsum) {
    __shared__ float s[4][16];
    const int tid = threadIdx.x;
    const int f = tid & 15;
    const float bf = b[f];
    float local = 0.f;
    for (int i = blockIdx.x * blockDim.x + tid; i < N_NODES * F_OUT;
         i += gridDim.x * blockDim.x) {
        const int n = i >> 4;
        local += tanhf(dinv[n] * (acc[i] + g[i]) + bf);
    }
    local += __shfl_down(local, 32);
    local += __shfl_down(local, 16);
    const int lane = tid & 63, wave = tid >> 6;
    if (lane < 16) s[wave][lane] = local;
    __syncthreads();
    if (tid < 16) {
        float v = s[0][tid] + s[1][tid] + s[2][tid] + s[3][tid];
        atomicAdd(&dsum[tid], (double)v);
    }
}

__global__ void out_kernel(const double* __restrict__ dsum, float* __restrict__ out) {
    const int f = threadIdx.x;
    if (f < 16) out[f] = (float)(dsum[f] * (1.0 / (double)N_NODES));
}

extern "C" void kernel_launch(void* const* d_in, const int* in_sizes, int n_in,
                              void* d_out, int out_size, void* d_ws, size_t ws_size,
                              hipStream_t stream) {
    const float* x  = (const float*)d_in[0];
    const int*   ei = (const int*)d_in[1];
    const float* W  = (const float*)d_in[2];
    const float* b  = (const float*)d_in[3];
    float* out = (float*)d_out;

    const int* row = ei;             // edge_index[0] = source
    const int* col = ei + N_EDGES;   // edge_index[1] = target

    // workspace layout (bytes):
    //   cnt/cursor : 100000 i32   (400000 B)   <- zeroed; later reused as cursor
    //   dsum       : 16 f64       (128 B)      <- zeroed (same memset)
    //   offs       : 100001 i32
    //   bsum       : 128 i32
    //   dinv       : 100000 f32
    //   srcs       : 6.4M i32     (25.6 MB)
    //   g          : 1.6M f32     (6.4 MB)
    //   acc        : 1.6M f32     (6.4 MB)
    char* p = (char*)d_ws;
    int*    cnt    = (int*)p;                 p += (size_t)N_NODES * 4;   // 400000
    double* dsum   = (double*)p;              p += 16 * 8;
    int*    offs   = (int*)p;                 p += (size_t)(N_NODES + 1) * 4;
    int*    bsum   = (int*)p;                 p += 128 * 4;
    float*  dinv   = (float*)p;               p += (size_t)N_NODES * 4;
    int*    srcs   = (int*)p;                 p += (size_t)N_EDGES * 4;
    float*  g      = (float*)p;               p += (size_t)N_NODES * F_OUT * 4;
    float*  acc    = (float*)p;
    int*    cursor = cnt;   // cnt is dead after dinv + scan_a

    hipMemsetAsync(cnt, 0, (size_t)N_NODES * 4 + 16 * 8, stream);  // cnt + dsum

    deg_kernel <<<(N_EDGES + 255) / 256, 256, 0, stream>>>(col, cnt);
    dinv_kernel<<<(N_NODES + 255) / 256, 256, 0, stream>>>(cnt, dinv);
    scan_a     <<<NBLK_SCAN, 256, 0, stream>>>(cnt, offs, bsum);
    scan_b     <<<1, 128, 0, stream>>>(bsum);
    scan_c     <<<(N_NODES + 255) / 256, 256, 0, stream>>>(offs, bsum, cursor);
    gemm_kernel<<<N_NODES / 16, 256, 0, stream>>>(x, W, dinv, g);
    fill_kernel<<<(N_EDGES + 255) / 256, 256, 0, stream>>>(row, col, cursor, srcs);
    gather_kernel<<<(N_NODES + 15) / 16, 256, 0, stream>>>(offs, srcs, g, acc);
    finalize_kernel<<<640, 256, 0, stream>>>(acc, g, dinv, b, dsum);
    out_kernel <<<1, 16, 0, stream>>>(dsum, out);
}

// Round 3
// 887.626 us; speedup vs baseline: 1.9508x; 1.1960x over previous
//
#include <hip/hip_runtime.h>
#include <math.h>

#define N_NODES 100000
#define N_EDGES 6400000
#define F_IN 128
#define F_OUT 16
#define NB 391                 // ceil(100000/256) buckets of 256 target nodes
#define KPB 3                  // scatter blocks per bucket
#define ACCN (NB * 256 * F_OUT)  // padded per-partial acc elements (1,601,536)
#define EPB3 16000             // edges per partition block: 400 * 16000 = 6.4M exactly

// -------- 1. global bucket histogram (LDS pre-aggregation) --------
__global__ void hist_kernel(const int* __restrict__ col, int* __restrict__ gbhist) {
    __shared__ int h[NB];
    const int tid = threadIdx.x;
    for (int i = tid; i < NB; i += 256) h[i] = 0;
    __syncthreads();
    const int stride = gridDim.x * 256;
    for (int e = blockIdx.x * 256 + tid; e < N_EDGES; e += stride)
        atomicAdd(&h[col[e] >> 8], 1);
    __syncthreads();
    for (int i = tid; i < NB; i += 256) if (h[i]) atomicAdd(&gbhist[i], h[i]);
}

// -------- 2. exclusive scan of 391 bucket counts (one block) --------
__global__ void scan_kernel(const int* __restrict__ gbhist, int* __restrict__ boffs,
                            int* __restrict__ gcursor) {
    __shared__ int lds[512];
    const int tid = threadIdx.x;
    int v = (tid < NB) ? gbhist[tid] : 0;
    lds[tid] = v; __syncthreads();
    for (int off = 1; off < 512; off <<= 1) {
        int t = (tid >= off) ? lds[tid - off] : 0; __syncthreads();
        lds[tid] += t; __syncthreads();
    }
    int excl = lds[tid] - v;
    if (tid < NB) { boffs[tid] = excl; gcursor[tid] = excl; }
    if (tid == NB) boffs[NB] = N_EDGES;
}

// -------- 3. partition edges into bucket-contiguous runs --------
// packed = (row << 8) | (col & 255): row < 2^17, local col < 2^8 -> fits 25 bits.
__global__ void part_kernel(const int* __restrict__ row, const int* __restrict__ col,
                            int* __restrict__ gcursor, unsigned int* __restrict__ packed) {
    __shared__ int hist[NB];
    __shared__ int base[NB];
    const int tid = threadIdx.x;
    const int e0 = blockIdx.x * EPB3, e1 = e0 + EPB3;
    for (int i = tid; i < NB; i += 256) hist[i] = 0;
    __syncthreads();
    for (int i = e0 + tid; i < e1; i += 256) atomicAdd(&hist[col[i] >> 8], 1);
    __syncthreads();
    for (int b = tid; b < NB; b += 256)
        base[b] = hist[b] ? atomicAdd(&gcursor[b], hist[b]) : 0;
    __syncthreads();
    for (int i = tid; i < NB; i += 256) hist[i] = 0;
    __syncthreads();
    for (int i = e0 + tid; i < e1; i += 256) {
        int c = col[i];
        int b = c >> 8;
        int p = base[b] + atomicAdd(&hist[b], 1);
        packed[p] = ((unsigned)row[i] << 8) | (unsigned)(c & 255);
    }
}

// -------- 4. per-bucket degree histogram -> dinv (no global atomics) --------
__global__ void deg_kernel(const unsigned int* __restrict__ packed,
                           const int* __restrict__ boffs, float* __restrict__ dinv) {
    __shared__ int dh[256];
    const int tid = threadIdx.x;
    dh[tid] = 0;
    __syncthreads();
    const int b = blockIdx.x;
    const int e = boffs[b + 1];
    for (int i = boffs[b] + tid; i < e; i += 256)
        atomicAdd(&dh[packed[i] & 255u], 1);
    __syncthreads();
    const int node = (b << 8) + tid;
    if (node < N_NODES) dinv[node] = rsqrtf((float)dh[tid] + 1.0f);  // +1 self loop
}

// -------- 5. g[n,f] = dinv[n] * sum_k x[n,k] * W[k,f] --------
__global__ void gemm_kernel(const float* __restrict__ x, const float* __restrict__ W,
                            const float* __restrict__ dinv, float* __restrict__ g) {
    __shared__ float Ws[F_IN * F_OUT];        // 8 KB
    __shared__ float xs[16 * (F_IN + 1)];
    const int tid = threadIdx.x;
    const int n0 = blockIdx.x * 16;
    for (int i = tid; i < F_IN * F_OUT; i += 256) Ws[i] = W[i];
    const float* xbase = x + (size_t)n0 * F_IN;
    for (int i = tid; i < 16 * F_IN; i += 256) {
        int r = i >> 7, c = i & 127;
        xs[r * (F_IN + 1) + c] = xbase[i];
    }
    __syncthreads();
    const int node = tid >> 4, f = tid & 15;
    const float* xr = &xs[node * (F_IN + 1)];
    float acc = 0.f;
    #pragma unroll 8
    for (int k = 0; k < F_IN; k++) acc += xr[k] * Ws[k * 16 + f];
    g[(size_t)n0 * 16 + tid] = acc * dinv[n0 + node];
}

// -------- 6. per-bucket scatter-reduce into LDS tile, flush to partials --------
__global__ void __launch_bounds__(256) scatter_kernel(
        const unsigned int* __restrict__ packed, const int* __restrict__ boffs,
        const float* __restrict__ g, float* __restrict__ accp) {
    __shared__ float sacc[256 * F_OUT];   // 16 KB
    const int tid = threadIdx.x;
    for (int i = tid; i < 256 * F_OUT; i += 256) sacc[i] = 0.f;
    __syncthreads();
    const int b = blockIdx.x, part = blockIdx.y;
    const int s = boffs[b], e = boffs[b + 1];
    const int chunk = (e - s + KPB - 1) / KPB;
    const int cs = s + part * chunk;
    const int ce = min(cs + chunk, e);
    const int f = tid & 15;
    int i = cs + (tid >> 4);              // 16 lanes per edge, 16 edges per step
    for (; i + 16 < ce; i += 32) {        // 2x unroll: 2 gathers in flight per lane
        unsigned p0 = packed[i], p1 = packed[i + 16];
        float v0 = g[(p0 >> 8) * 16 + f];
        float v1 = g[(p1 >> 8) * 16 + f];
        atomicAdd(&sacc[((p0 & 255u) << 4) + f], v0);
        atomicAdd(&sacc[((p1 & 255u) << 4) + f], v1);
    }
    if (i < ce) {
        unsigned p0 = packed[i];
        atomicAdd(&sacc[((p0 & 255u) << 4) + f], g[(p0 >> 8) * 16 + f]);
    }
    __syncthreads();
    float* dst = accp + (size_t)part * ACCN + ((size_t)(b << 8)) * F_OUT;
    const int nbase = b << 8;
    for (int j = tid; j < 256 * F_OUT; j += 256)
        if (nbase + (j >> 4) < N_NODES) dst[j] = sacc[j];
}

// -------- 7. out_n = tanh(dinv[n]*(acc(n)+g[n]) + b); mean over n --------
__global__ void finalize_kernel(const float* __restrict__ accp, const float* __restrict__ g,
                                const float* __restrict__ dinv, const float* __restrict__ b,
                                double* __restrict__ dsum) {
    __shared__ float s[4][16];
    const int tid = threadIdx.x;
    const int f = tid & 15;
    const float bf = b[f];
    float local = 0.f;
    for (int i = blockIdx.x * blockDim.x + tid; i < N_NODES * F_OUT;
         i += gridDim.x * blockDim.x) {
        const int n = i >> 4;
        float a = accp[i] + accp[ACCN + i] + accp[2 * ACCN + i] + g[i];
        local += tanhf(dinv[n] * a + bf);
    }
    local += __shfl_down(local, 32);
    local += __shfl_down(local, 16);
    const int lane = tid & 63, wave = tid >> 6;
    if (lane < 16) s[wave][lane] = local;
    __syncthreads();
    if (tid < 16) {
        float v = s[0][tid] + s[1][tid] + s[2][tid] + s[3][tid];
        atomicAdd(&dsum[tid], (double)v);
    }
}

__global__ void out_kernel(const double* __restrict__ dsum, float* __restrict__ out) {
    const int f = threadIdx.x;
    if (f < 16) out[f] = (float)(dsum[f] * (1.0 / (double)N_NODES));
}

extern "C" void kernel_launch(void* const* d_in, const int* in_sizes, int n_in,
                              void* d_out, int out_size, void* d_ws, size_t ws_size,
                              hipStream_t stream) {
    const float* x  = (const float*)d_in[0];
    const int*   ei = (const int*)d_in[1];
    const float* W  = (const float*)d_in[2];
    const float* b  = (const float*)d_in[3];
    float* out = (float*)d_out;

    const int* row = ei;             // edge_index[0] = source
    const int* col = ei + N_EDGES;   // edge_index[1] = target

    // workspace layout (~51.6 MB):
    char* p = (char*)d_ws;
    double*       dsum    = (double*)p;        p += 16 * 8;
    int*          gbhist  = (int*)p;           p += NB * 4;
    int*          gcursor = (int*)p;           p += NB * 4;
    int*          boffs   = (int*)p;           p += (NB + 1) * 4;
    float*        dinv    = (float*)p;         p += (size_t)N_NODES * 4;
    float*        g       = (float*)p;         p += (size_t)N_NODES * F_OUT * 4;
    unsigned int* packed  = (unsigned int*)p;  p += (size_t)N_EDGES * 4;
    float*        accp    = (float*)p;         // KPB * ACCN floats (19.2 MB)

    // zero dsum + gbhist (contiguous)
    hipMemsetAsync(dsum, 0, 16 * 8 + NB * 4, stream);

    hist_kernel    <<<400, 256, 0, stream>>>(col, gbhist);
    scan_kernel    <<<1, 512, 0, stream>>>(gbhist, boffs, gcursor);
    part_kernel    <<<400, 256, 0, stream>>>(row, col, gcursor, packed);
    deg_kernel     <<<NB, 256, 0, stream>>>(packed, boffs, dinv);
    gemm_kernel    <<<N_NODES / 16, 256, 0, stream>>>(x, W, dinv, g);
    scatter_kernel <<<dim3(NB, KPB), 256, 0, stream>>>(packed, boffs, g, accp);
    finalize_kernel<<<640, 256, 0, stream>>>(accp, g, dinv, b, dsum);
    out_kernel     <<<1, 16, 0, stream>>>(dsum, out);
}